// Round 9
// baseline (442.247 us; speedup 1.0000x reference)
//
#include <hip/hip_runtime.h>
#include <hip/hip_bf16.h>

#define S_LEN 2048
#define NH 8
#define HD 64
#define CH 512
#define NEG_BIG (-3.0e38f)
#define KHALF 1024                          // attn split-K x2
#define CTXP_STRIDE (2 * NH * S_LEN * HD)   // floats per split partial
#define ML_STRIDE   (2 * NH * S_LEN)        // (m,l) rows per split
#define LDS_T (128 * 36)                    // one gemm LDS buffer (bf16 elems)
#define OUTP_STRIDE (4096 * 512)            // floats per out split partial

typedef __bf16 bf16;
typedef bf16 bf16x8 __attribute__((ext_vector_type(8)));
typedef bf16 bf16x4 __attribute__((ext_vector_type(4)));
typedef float floatx4 __attribute__((ext_vector_type(4)));

// global_load_lds width-16 helper (wave-uniform LDS base + lane*16)
typedef const unsigned int __attribute__((address_space(1)))* gas1_t;
typedef unsigned int __attribute__((address_space(3)))* las3_t;
__device__ __forceinline__ void gll16(const void* g, void* l) {
    __builtin_amdgcn_global_load_lds((gas1_t)g, (las3_t)l, 16, 0, 0);
}

// ---------------------------------------------------------------------------
// Mask dtype detection: 0=int32, 1=uint8, 2=float32.
// ---------------------------------------------------------------------------
__global__ void detect_mask_kernel(const unsigned char* __restrict__ mb,
                                   int* __restrict__ flag_out) {
    __shared__ int s1, s3;
    if (threadIdx.x == 0) { s1 = 0; s3 = 0; }
    __syncthreads();
    int any1 = 0, any3 = 0;
    int base = threadIdx.x * 16;
    for (int i = base; i < base + 16; ++i) {
        unsigned char bch = mb[i];
        int m = i & 3;
        if (bch != 0) {
            if (m == 1) any1 = 1;
            if (m == 2 || m == 3) any3 = 1;
        }
    }
    if (any1) atomicOr(&s1, 1);
    if (any3) atomicOr(&s3, 1);
    __syncthreads();
    if (threadIdx.x == 0) {
        int f = 0;
        if (s1) f = 1;
        else if (s3) f = 2;
        *flag_out = f;
    }
}

// ---------------------------------------------------------------------------
// Weight prep: W [K][N] fp32 -> WT_hi/WT_lo bf16 [N][K] (hi/lo split).
// ---------------------------------------------------------------------------
__global__ __launch_bounds__(256) void prep_weights_kernel(
    const float* __restrict__ Wq, const float* __restrict__ Wk,
    const float* __restrict__ Wv, const float* __restrict__ Wo,
    bf16* __restrict__ WThi, bf16* __restrict__ WTlo)
{
    __shared__ float tile[64][65];
    const int t = threadIdx.x;
    const int n0 = blockIdx.x * 64;
    const int k0 = blockIdx.y * 64;
    const int mat = blockIdx.z;
    const float* W = (mat == 0) ? Wq : (mat == 1) ? Wk : (mat == 2) ? Wv : Wo;
    bf16* hi = WThi + (size_t)mat * (CH * CH);
    bf16* lo = WTlo + (size_t)mat * (CH * CH);
#pragma unroll
    for (int i = 0; i < 4; ++i) {
        int row = (t >> 4) + 16 * i;
        int c4 = (t & 15) << 2;
        float4 f = *(const float4*)(W + (size_t)(k0 + row) * CH + n0 + c4);
        tile[row][c4 + 0] = f.x; tile[row][c4 + 1] = f.y;
        tile[row][c4 + 2] = f.z; tile[row][c4 + 3] = f.w;
    }
    __syncthreads();
#pragma unroll
    for (int i = 0; i < 4; ++i) {
        int nr = (t >> 4) + 16 * i;
        int k4 = (t & 15) << 2;
        bf16x4 h, l;
#pragma unroll
        for (int j = 0; j < 4; ++j) {
            float x = tile[k4 + j][nr];
            bf16 hv = (bf16)x;
            h[j] = hv;
            l[j] = (bf16)(x - (float)hv);
        }
        *(bf16x4*)(hi + (size_t)(n0 + nr) * CH + k0 + k4) = h;
        *(bf16x4*)(lo + (size_t)(n0 + nr) * CH + k0 + k4) = l;
    }
}

// ---------------------------------------------------------------------------
// bf16-MFMA GEMM, hi/lo split, DOUBLE-BUFFERED single-barrier pipeline:
//   per K-step: compute(buf) -> stage(regs -> buf^1) -> issue loads(k+2)
//   -> ONE barrier. HBM latency hides under the 48-MFMA compute phase.
// 128x128 tile, BK=32, 256 thr = 4 waves. LDS stride 36 shorts (72B,
// 2-way bank alias = free); 8 buffers x 9 KB = 72 KB -> 2 blocks/CU.
// mode 0: OUT fp32 [b,h,s,d] (+BI, *scale)
// mode 2: OUT fp32 flat [row,512]; BI may be null (raw partial for split-K);
//         ML != nullptr fuses the 2-way attn split-softmax merge into loadA.
// mode 3: OBF bf16 [b,h,s, d-swizzled] (K: 16B group g stored at g ^ (s&7))
// mode 4: OBF bf16 [b,h,d, s-chunk-swizzled] (V^T: per 64-k chunk, g ^= d&7)
// ---------------------------------------------------------------------------
__device__ __forceinline__ void gemm_bf16_tile(
    bf16* __restrict__ As_hi, bf16* __restrict__ As_lo,
    bf16* __restrict__ Bs_hi, bf16* __restrict__ Bs_lo,
    const float* __restrict__ IN, const bf16* __restrict__ WThi,
    const bf16* __restrict__ WTlo, const float* __restrict__ BI,
    float* __restrict__ OUT, bf16* __restrict__ OBF,
    const float* __restrict__ ML, float scale, int mode,
    int kbeg, int kiters)
{
    const int t = threadIdx.x;
    const int w = t >> 6;
    const int lane = t & 63;
    const int m16 = lane & 15;
    const int quad = lane >> 4;
    const int m0 = blockIdx.y * 128;
    const int n0 = blockIdx.x * 128;

    const int arow = t >> 1;           // 0..127
    const int akc  = (t & 1) << 4;     // 0 or 16

    floatx4 acc[2][8];
#pragma unroll
    for (int mi = 0; mi < 2; ++mi)
#pragma unroll
        for (int ni = 0; ni < 8; ++ni) {
            acc[mi][ni][0] = 0.f; acc[mi][ni][1] = 0.f;
            acc[mi][ni][2] = 0.f; acc[mi][ni][3] = 0.f;
        }

    float4 af[4];
    bf16x8 pbh[2], pbl[2];

    auto loadA = [&](int k0) {
        if (ML) {
            // fused split-K merge: IN = ctxp [split][b,h,s,d]
            int col = k0 + akc;
            int hh = col >> 6, dd = col & 63;
            int row = m0 + arow;
            int bb = row >> 11, ss = row & (S_LEN - 1);
            size_t prow = ((size_t)bb * NH + hh) * S_LEN + ss;
            float m0v = ML[prow * 2],                 l0v = ML[prow * 2 + 1];
            float m1v = ML[(ML_STRIDE + prow) * 2],   l1v = ML[(ML_STRIDE + prow) * 2 + 1];
            float mx = fmaxf(m0v, m1v);
            float e0 = __expf(m0v - mx), e1 = __expf(m1v - mx);
            float den = e0 * l0v + e1 * l1v;
            float inv = den > 0.f ? 1.f / den : 0.f;
            float a0 = e0 * inv, a1 = e1 * inv;
            const float* p0 = IN + prow * HD + dd;
            const float* p1 = p0 + CTXP_STRIDE;
#pragma unroll
            for (int j = 0; j < 4; ++j) {
                float4 c0 = ((const float4*)p0)[j];
                float4 c1 = ((const float4*)p1)[j];
                af[j].x = a0 * c0.x + a1 * c1.x;
                af[j].y = a0 * c0.y + a1 * c1.y;
                af[j].z = a0 * c0.z + a1 * c1.z;
                af[j].w = a0 * c0.w + a1 * c1.w;
            }
        } else {
            const float* p = IN + (size_t)(m0 + arow) * CH + k0 + akc;
            af[0] = ((const float4*)p)[0];
            af[1] = ((const float4*)p)[1];
            af[2] = ((const float4*)p)[2];
            af[3] = ((const float4*)p)[3];
        }
    };
    auto loadB = [&](int k0) {
        const bf16* ph = WThi + (size_t)(n0 + arow) * CH + k0 + akc;
        const bf16* pl = WTlo + (size_t)(n0 + arow) * CH + k0 + akc;
        pbh[0] = ((const bf16x8*)ph)[0]; pbh[1] = ((const bf16x8*)ph)[1];
        pbl[0] = ((const bf16x8*)pl)[0]; pbl[1] = ((const bf16x8*)pl)[1];
    };
    auto stage = [&](int buf) {
        int base = buf * LDS_T;
#pragma unroll
        for (int hh = 0; hh < 2; ++hh) {
            bf16x8 h, l;
#pragma unroll
            for (int j = 0; j < 8; ++j) {
                float x = ((const float*)&af[2 * hh])[j];
                bf16 hv = (bf16)x;
                h[j] = hv;
                l[j] = (bf16)(x - (float)hv);
            }
            *(bf16x8*)&As_hi[base + arow * 36 + akc + 8 * hh] = h;
            *(bf16x8*)&As_lo[base + arow * 36 + akc + 8 * hh] = l;
        }
        *(bf16x8*)&Bs_hi[base + arow * 36 + akc + 0] = pbh[0];
        *(bf16x8*)&Bs_hi[base + arow * 36 + akc + 8] = pbh[1];
        *(bf16x8*)&Bs_lo[base + arow * 36 + akc + 0] = pbl[0];
        *(bf16x8*)&Bs_lo[base + arow * 36 + akc + 8] = pbl[1];
    };

    // prologue: fill buf0, pre-issue loads for step 1
    loadA(kbeg); loadB(kbeg);
    stage(0);
    if (kiters > 1) { loadA(kbeg + 32); loadB(kbeg + 32); }
    __syncthreads();
    int cur = 0;

    for (int ks = 0; ks < kiters; ++ks) {
        int cb = cur * LDS_T;
        bf16x8 bh[8], bl[8];
#pragma unroll
        for (int ni = 0; ni < 8; ++ni) {
            bh[ni] = *(const bf16x8*)&Bs_hi[cb + (16 * ni + m16) * 36 + 8 * quad];
            bl[ni] = *(const bf16x8*)&Bs_lo[cb + (16 * ni + m16) * 36 + 8 * quad];
        }
#pragma unroll
        for (int mi = 0; mi < 2; ++mi) {
            bf16x8 ah = *(const bf16x8*)&As_hi[cb + (32 * w + 16 * mi + m16) * 36 + 8 * quad];
            bf16x8 al = *(const bf16x8*)&As_lo[cb + (32 * w + 16 * mi + m16) * 36 + 8 * quad];
#pragma unroll
            for (int ni = 0; ni < 8; ++ni) {
                acc[mi][ni] = __builtin_amdgcn_mfma_f32_16x16x32_bf16(ah, bh[ni], acc[mi][ni], 0, 0, 0);
                acc[mi][ni] = __builtin_amdgcn_mfma_f32_16x16x32_bf16(ah, bl[ni], acc[mi][ni], 0, 0, 0);
                acc[mi][ni] = __builtin_amdgcn_mfma_f32_16x16x32_bf16(al, bh[ni], acc[mi][ni], 0, 0, 0);
            }
        }
        if (ks + 1 < kiters) {
            stage(cur ^ 1);   // regs loaded >=1 full compute phase ago
            if (ks + 2 < kiters) { loadA(kbeg + 32 * (ks + 2)); loadB(kbeg + 32 * (ks + 2)); }
        }
        __syncthreads();      // reads of buf[cur] done + stage(buf^1) visible
        cur ^= 1;
    }

#pragma unroll
    for (int mi = 0; mi < 2; ++mi) {
#pragma unroll
        for (int r = 0; r < 4; ++r) {
            int row = m0 + 32 * w + 16 * mi + 4 * quad + r;
            int bb = row >> 11;
            int ss = row & (S_LEN - 1);
#pragma unroll
            for (int ni = 0; ni < 8; ++ni) {
                int col = n0 + 16 * ni + m16;
                float v = BI ? (acc[mi][ni][r] + BI[col]) * scale
                             : acc[mi][ni][r] * scale;
                if (mode == 0) {
                    int hh = col >> 6, dd = col & 63;
                    OUT[(((size_t)bb * NH + hh) * S_LEN + ss) * HD + dd] = v;
                } else if (mode == 3) {
                    int hh = col >> 6, dd = col & 63;
                    OBF[((size_t)(bb * NH + hh) * S_LEN + ss) * HD
                        + (((dd >> 3) ^ (ss & 7)) << 3) + (dd & 7)] = (bf16)v;
                } else if (mode == 4) {
                    int hh = col >> 6, dd = col & 63;
                    OBF[((size_t)(bb * NH + hh) * HD + dd) * S_LEN
                        + (ss & ~63) + ((((ss >> 3) & 7) ^ (dd & 7)) << 3) + (ss & 7)] = (bf16)v;
                } else {
                    OUT[(size_t)row * CH + col] = v;
                }
            }
        }
    }
}

__global__ __launch_bounds__(256, 2) void qkv_gemm_kernel(
    const float* __restrict__ q_in, const float* __restrict__ k_in,
    const float* __restrict__ v_in,
    const bf16* __restrict__ WThi, const bf16* __restrict__ WTlo,
    const float* __restrict__ bq, const float* __restrict__ bk,
    const float* __restrict__ bv,
    float* __restrict__ qp, bf16* __restrict__ kswz, bf16* __restrict__ vswz)
{
    __shared__ __attribute__((aligned(16))) bf16 As_hi[2 * LDS_T];
    __shared__ __attribute__((aligned(16))) bf16 As_lo[2 * LDS_T];
    __shared__ __attribute__((aligned(16))) bf16 Bs_hi[2 * LDS_T];
    __shared__ __attribute__((aligned(16))) bf16 Bs_lo[2 * LDS_T];
    int z = blockIdx.z;
    if (z == 0)
        gemm_bf16_tile(As_hi, As_lo, Bs_hi, Bs_lo, q_in,
                       WThi, WTlo, bq, qp, nullptr, nullptr, 0.125f, 0, 0, 16);
    else if (z == 1)
        gemm_bf16_tile(As_hi, As_lo, Bs_hi, Bs_lo, k_in,
                       WThi + (size_t)CH * CH, WTlo + (size_t)CH * CH, bk,
                       nullptr, kswz, nullptr, 1.0f, 3, 0, 16);
    else
        gemm_bf16_tile(As_hi, As_lo, Bs_hi, Bs_lo, v_in,
                       WThi + (size_t)2 * CH * CH, WTlo + (size_t)2 * CH * CH, bv,
                       nullptr, vswz, nullptr, 1.0f, 4, 0, 16);
}

// out GEMM: split-K x2 into private partials (z = split), fused (m,l) merge.
__global__ __launch_bounds__(256, 2) void out_gemm_kernel(
    const float* __restrict__ ctxp, const float* __restrict__ ml,
    const bf16* __restrict__ WThi, const bf16* __restrict__ WTlo,
    float* __restrict__ outp)
{
    __shared__ __attribute__((aligned(16))) bf16 As_hi[2 * LDS_T];
    __shared__ __attribute__((aligned(16))) bf16 As_lo[2 * LDS_T];
    __shared__ __attribute__((aligned(16))) bf16 Bs_hi[2 * LDS_T];
    __shared__ __attribute__((aligned(16))) bf16 Bs_lo[2 * LDS_T];
    int z = blockIdx.z;
    gemm_bf16_tile(As_hi, As_lo, Bs_hi, Bs_lo, ctxp,
                   WThi + (size_t)3 * CH * CH, WTlo + (size_t)3 * CH * CH,
                   nullptr, outp + (size_t)z * OUTP_STRIDE, nullptr, ml,
                   1.0f, 2, z * 256, 8);
}

// out = partial0 + partial1 + bo
__global__ __launch_bounds__(256) void add_out_kernel(
    const float* __restrict__ outp, const float* __restrict__ bo,
    float* __restrict__ out)
{
    int idx = blockIdx.x * 256 + threadIdx.x;       // one float4
    int col4 = (idx & 127) << 2;
    float4 a = ((const float4*)outp)[idx];
    float4 b = ((const float4*)(outp + OUTP_STRIDE))[idx];
    float4 c = *(const float4*)(bo + col4);
    float4 o;
    o.x = a.x + b.x + c.x;
    o.y = a.y + b.y + c.y;
    o.z = a.z + b.z + c.z;
    o.w = a.w + b.w + c.w;
    ((float4*)out)[idx] = o;
}

// ---------------------------------------------------------------------------
// Flash attention, split-K x2, double-buffered K/V staging (R6, unchanged):
// stage(t+1 -> buf^1) issued BEFORE compute(t); ONE barrier per tile.
// Reuse-aligned XCD swizzle. bias+mask prefetched per-lane in regs.
// ---------------------------------------------------------------------------
__global__ __launch_bounds__(256, 4) void attn_kernel(
    const float* __restrict__ qp, const bf16* __restrict__ kswz,
    const bf16* __restrict__ vswz, const float* __restrict__ bias,
    const void* __restrict__ mask, const int* __restrict__ flagp,
    float* __restrict__ ctxp, float* __restrict__ ml)
{
    __shared__ __attribute__((aligned(16))) bf16 Kt[2][64 * 64];
    __shared__ __attribute__((aligned(16))) bf16 Vt[2][64 * 64];
    __shared__ __attribute__((aligned(16))) bf16 Pbf[64 * 72];

    const int t    = threadIdx.x;
    const int w    = t >> 6;
    const int lane = t & 63;
    const int m16  = lane & 15;
    const int quad = lane >> 4;
    const int mx7  = m16 & 7;

    // physical -> logical block id (bijective: 1024 = 8 XCDs x 128)
    const int p  = blockIdx.x + 32 * (blockIdx.y + 8 * blockIdx.z);
    const int l  = (p & 7) * 128 + (p >> 3);
    const int b  = l & 1;
    const int kz = (l >> 1) & 1;
    const int h  = (l >> 2) & 7;
    const int qi = l >> 5;

    const int q0   = qi * 64;
    const int bh   = b * NH + h;
    const int flag = *flagp;
    const int kbeg = kz * KHALF;

    // Q fragments (prescaled by 1/8 in projection)
    bf16x8 qf[2];
    {
        const float* qrow =
            qp + ((size_t)bh * S_LEN + q0 + 16 * w + m16) * HD + 8 * quad;
#pragma unroll
        for (int c = 0; c < 2; ++c) {
            float4 f0 = *(const float4*)(qrow + 32 * c);
            float4 f1 = *(const float4*)(qrow + 32 * c + 4);
            bf16x8 v;
            v[0] = (bf16)f0.x; v[1] = (bf16)f0.y; v[2] = (bf16)f0.z; v[3] = (bf16)f0.w;
            v[4] = (bf16)f1.x; v[5] = (bf16)f1.y; v[6] = (bf16)f1.z; v[7] = (bf16)f1.w;
            qf[c] = v;
        }
    }

    floatx4 ctxa[4];
    float mrow[4], lrow[4];
#pragma unroll
    for (int tt = 0; tt < 4; ++tt) { ctxa[tt][0]=0.f; ctxa[tt][1]=0.f; ctxa[tt][2]=0.f; ctxa[tt][3]=0.f; }
#pragma unroll
    for (int r = 0; r < 4; ++r) { mrow[r] = NEG_BIG; lrow[r] = 0.f; }

    // per-lane bias/mask prefetch in softmax layout: rows qrow0+r, cols k0+16tt+m16
    const int qrow0 = q0 + 16 * w + 4 * quad;
    const float* bbase = bias + ((size_t)h * S_LEN + qrow0) * S_LEN + m16;
    const unsigned char* mb8  = (const unsigned char*)mask + (size_t)qrow0 * S_LEN + m16;
    const unsigned int*  mb32 = (const unsigned int*)mask  + (size_t)qrow0 * S_LEN + m16;

    float bnext[16]; unsigned mnext[16]; float mb[16];
    auto prefetchBM = [&](int k0) {
        if (flag == 1) {
#pragma unroll
            for (int r = 0; r < 4; ++r)
#pragma unroll
                for (int tt = 0; tt < 4; ++tt)
                    mnext[4 * r + tt] = mb8[(size_t)r * S_LEN + k0 + 16 * tt];
        } else {
#pragma unroll
            for (int r = 0; r < 4; ++r)
#pragma unroll
                for (int tt = 0; tt < 4; ++tt)
                    mnext[4 * r + tt] = mb32[(size_t)r * S_LEN + k0 + 16 * tt];
        }
#pragma unroll
        for (int r = 0; r < 4; ++r)
#pragma unroll
            for (int tt = 0; tt < 4; ++tt)
                bnext[4 * r + tt] = bbase[(size_t)r * S_LEN + k0 + 16 * tt];
    };

    const bf16* kb = kswz + (size_t)bh * S_LEN * HD;
    const bf16* vb = vswz + (size_t)bh * HD * S_LEN;
    const int lrow8 = lane >> 3;         // row within 8-row chunk
    const int lcol8 = (lane & 7) * 8;    // bf16 offset of 16B group

    // wave w stages chunks {2w, 2w+1} (8 rows x 128B each) of K and V
    auto stageKV = [&](int k0, int buf) {
#pragma unroll
        for (int i = 0; i < 2; ++i) {
            int c = 2 * w + i;
            int row = 8 * c + lrow8;
            gll16(kb + (size_t)(k0 + row) * HD + lcol8, &Kt[buf][c * 512]);
            gll16(vb + (size_t)row * S_LEN + k0 + lcol8, &Vt[buf][c * 512]);
        }
    };

    prefetchBM(kbeg);
    stageKV(kbeg, 0);
    __syncthreads();           // drains the prologue stage (vmcnt(0) implicit)
    int cur = 0;

    for (int k0 = kbeg; k0 < kbeg + KHALF; k0 += 64) {
        const bool more = (k0 + 64 < kbeg + KHALF);
        if (more) stageKV(k0 + 64, cur ^ 1);   // issue next tile into other buf

        // select masked bias for this tile, then prefetch next (overlaps compute)
#pragma unroll
        for (int j = 0; j < 16; ++j) mb[j] = mnext[j] ? bnext[j] : NEG_BIG;
        if (more) prefetchBM(k0 + 64);

        // QK^T  (Kt read with XOR(g, row&7) de-swizzle)
        const bf16* Kc = Kt[cur];
        const bf16* Vc = Vt[cur];
        floatx4 sc[4];
#pragma unroll
        for (int tt = 0; tt < 4; ++tt) { sc[tt][0]=0.f; sc[tt][1]=0.f; sc[tt][2]=0.f; sc[tt][3]=0.f; }
#pragma unroll
        for (int st = 0; st < 2; ++st)
#pragma unroll
            for (int tt = 0; tt < 4; ++tt) {
                bf16x8 kf = *(const bf16x8*)&Kc[(16 * tt + m16) * 64
                                                + (((quad + 4 * st) ^ mx7) << 3)];
                sc[tt] = __builtin_amdgcn_mfma_f32_16x16x32_bf16(qf[st], kf, sc[tt], 0, 0, 0);
            }

        // online softmax (bias/mask already in regs)
        float alpha[4];
#pragma unroll
        for (int r = 0; r < 4; ++r) {
            int lrowq = 16 * w + 4 * quad + r;
            float s[4];
#pragma unroll
            for (int tt = 0; tt < 4; ++tt)
                s[tt] = sc[tt][r] + mb[4 * r + tt];
            float mx = fmaxf(fmaxf(s[0], s[1]), fmaxf(s[2], s[3]));
            mx = fmaxf(mx, __shfl_xor(mx, 1));
            mx = fmaxf(mx, __shfl_xor(mx, 2));
            mx = fmaxf(mx, __shfl_xor(mx, 4));
            mx = fmaxf(mx, __shfl_xor(mx, 8));
            float mnew = fmaxf(mrow[r], mx);
            float al = __expf(mrow[r] - mnew);
            float ls = 0.f;
#pragma unroll
            for (int tt = 0; tt < 4; ++tt) {
                float px = (s[tt] <= -1e37f) ? 0.f : __expf(s[tt] - mnew);
                ls += px;
                Pbf[lrowq * 72 + 16 * tt + m16] = (bf16)px;
            }
            ls += __shfl_xor(ls, 1);
            ls += __shfl_xor(ls, 2);
            ls += __shfl_xor(ls, 4);
            ls += __shfl_xor(ls, 8);
            lrow[r] = lrow[r] * al + ls;
            mrow[r] = mnew;
            alpha[r] = al;
        }
#pragma unroll
        for (int tt = 0; tt < 4; ++tt)
#pragma unroll
            for (int r = 0; r < 4; ++r) ctxa[tt][r] *= alpha[r];

        // PV (Pbf rows 16w..16w+15 wave-private -> no barrier vs softmax)
#pragma unroll
        for (int st = 0; st < 2; ++st) {
            bf16x8 pf = *(const bf16x8*)&Pbf[(16 * w + m16) * 72 + 8 * quad + 32 * st];
#pragma unroll
            for (int tt = 0; tt < 4; ++tt) {
                bf16x8 vf = *(const bf16x8*)&Vc[(16 * tt + m16) * 64
                                                + (((quad + 4 * st) ^ mx7) << 3)];
                ctxa[tt] = __builtin_amdgcn_mfma_f32_16x16x32_bf16(pf, vf, ctxa[tt], 0, 0, 0);
            }
        }

        __syncthreads();
        cur ^= 1;
    }

    // epilogue: unnormalized partial ctx + (m,l) for this split
    float* cp = ctxp + (size_t)kz * CTXP_STRIDE;
#pragma unroll
    for (int r = 0; r < 4; ++r) {
        int grow = q0 + 16 * w + 4 * quad + r;
        size_t prow = (size_t)bh * S_LEN + grow;
#pragma unroll
        for (int tt = 0; tt < 4; ++tt)
            cp[prow * HD + 16 * tt + m16] = ctxa[tt][r];
        if (m16 == 0) {
            ml[((size_t)kz * ML_STRIDE + prow) * 2 + 0] = mrow[r];
            ml[((size_t)kz * ML_STRIDE + prow) * 2 + 1] = lrow[r];
        }
    }
}

extern "C" void kernel_launch(void* const* d_in, const int* in_sizes, int n_in,
                              void* d_out, int out_size, void* d_ws, size_t ws_size,
                              hipStream_t stream) {
    const float* k_in = (const float*)d_in[0];
    const float* v_in = (const float*)d_in[1];
    const float* q_in = (const float*)d_in[2];
    const void*  mask = d_in[3];
    const float* bias = (const float*)d_in[4];
    const float* Wq = (const float*)d_in[5];
    const float* bq = (const float*)d_in[6];
    const float* Wk = (const float*)d_in[7];
    const float* bk = (const float*)d_in[8];
    const float* Wv = (const float*)d_in[9];
    const float* bv = (const float*)d_in[10];
    const float* Wo = (const float*)d_in[11];
    const float* bo = (const float*)d_in[12];
    float* out = (float*)d_out;

    // Workspace 53 MB (+4 B). ws_size >= 54 MB proven in round 5.
    char* base = (char*)d_ws;
    float* qp   = (float*)(base);                    // 8 MB [B,H,S,D] fp32
    float* ctxp = (float*)(base + (8u  << 20));      // 16 MB attn partials
    float* mlb  = (float*)(base + (24u << 20));      // 0.5 MB (m,l) x 2 splits
    bf16*  kswz = (bf16*) (base + (25u << 20));      // 4 MB K bf16 swizzled
    bf16*  vswz = (bf16*) (base + (29u << 20));      // 4 MB V^T bf16 swizzled
    bf16*  WThi = (bf16*) (base + (33u << 20));      // 2 MB
    bf16*  WTlo = (bf16*) (base + (35u << 20));      // 2 MB
    float* outp = (float*)(base + (37u << 20));      // 16 MB out partials (2x8)
    int*   flag = (int*)  (base + (53u << 20));

    detect_mask_kernel<<<1, 256, 0, stream>>>((const unsigned char*)mask, flag);
    prep_weights_kernel<<<dim3(8, 8, 4), 256, 0, stream>>>(
        Wq, Wk, Wv, Wo, WThi, WTlo);
    qkv_gemm_kernel<<<dim3(4, 32, 3), 256, 0, stream>>>(
        q_in, k_in, v_in, WThi, WTlo, bq, bk, bv, qp, kswz, vswz);
    attn_kernel<<<dim3(32, 8, 4), 256, 0, stream>>>(
        qp, kswz, vswz, bias, mask, flag, ctxp, mlb);
    out_gemm_kernel<<<dim3(4, 32, 2), 256, 0, stream>>>(
        ctxp, mlb, WThi, WTlo, outp);
    add_out_kernel<<<2048, 256, 0, stream>>>(outp, bo, out);
}

// Round 11
// 357.819 us; speedup vs baseline: 1.2360x; 1.2360x over previous
//
#include <hip/hip_runtime.h>
#include <hip/hip_bf16.h>

#define S_LEN 2048
#define NH 8
#define HD 64
#define CH 512
#define NEG_BIG (-3.0e38f)
#define KHALF 1024                          // attn split-K x2
#define CTXP_STRIDE (2 * NH * S_LEN * HD)   // floats per split partial
#define ML_STRIDE   (2 * NH * S_LEN)        // (m,l) rows per split
#define OUTP_STRIDE (4096 * 512)            // floats per out split partial

typedef __bf16 bf16;
typedef bf16 bf16x8 __attribute__((ext_vector_type(8)));
typedef bf16 bf16x4 __attribute__((ext_vector_type(4)));
typedef float floatx4 __attribute__((ext_vector_type(4)));

// global_load_lds width-16 helper (wave-uniform LDS base + lane*16)
typedef const unsigned int __attribute__((address_space(1)))* gas1_t;
typedef unsigned int __attribute__((address_space(3)))* las3_t;
__device__ __forceinline__ void gll16(const void* g, void* l) {
    __builtin_amdgcn_global_load_lds((gas1_t)g, (las3_t)l, 16, 0, 0);
}

// ---------------------------------------------------------------------------
// Mask dtype detection: 0=int32, 1=uint8, 2=float32.
// ---------------------------------------------------------------------------
__global__ void detect_mask_kernel(const unsigned char* __restrict__ mb,
                                   int* __restrict__ flag_out) {
    __shared__ int s1, s3;
    if (threadIdx.x == 0) { s1 = 0; s3 = 0; }
    __syncthreads();
    int any1 = 0, any3 = 0;
    int base = threadIdx.x * 16;
    for (int i = base; i < base + 16; ++i) {
        unsigned char bch = mb[i];
        int m = i & 3;
        if (bch != 0) {
            if (m == 1) any1 = 1;
            if (m == 2 || m == 3) any3 = 1;
        }
    }
    if (any1) atomicOr(&s1, 1);
    if (any3) atomicOr(&s3, 1);
    __syncthreads();
    if (threadIdx.x == 0) {
        int f = 0;
        if (s1) f = 1;
        else if (s3) f = 2;
        *flag_out = f;
    }
}

// ---------------------------------------------------------------------------
// Weight prep: W [K][N] fp32 -> WT_hi/WT_lo bf16 [N][K] (hi/lo split).
// ---------------------------------------------------------------------------
__global__ __launch_bounds__(256) void prep_weights_kernel(
    const float* __restrict__ Wq, const float* __restrict__ Wk,
    const float* __restrict__ Wv, const float* __restrict__ Wo,
    bf16* __restrict__ WThi, bf16* __restrict__ WTlo)
{
    __shared__ float tile[64][65];
    const int t = threadIdx.x;
    const int n0 = blockIdx.x * 64;
    const int k0 = blockIdx.y * 64;
    const int mat = blockIdx.z;
    const float* W = (mat == 0) ? Wq : (mat == 1) ? Wk : (mat == 2) ? Wv : Wo;
    bf16* hi = WThi + (size_t)mat * (CH * CH);
    bf16* lo = WTlo + (size_t)mat * (CH * CH);
#pragma unroll
    for (int i = 0; i < 4; ++i) {
        int row = (t >> 4) + 16 * i;
        int c4 = (t & 15) << 2;
        float4 f = *(const float4*)(W + (size_t)(k0 + row) * CH + n0 + c4);
        tile[row][c4 + 0] = f.x; tile[row][c4 + 1] = f.y;
        tile[row][c4 + 2] = f.z; tile[row][c4 + 3] = f.w;
    }
    __syncthreads();
#pragma unroll
    for (int i = 0; i < 4; ++i) {
        int nr = (t >> 4) + 16 * i;
        int k4 = (t & 15) << 2;
        bf16x4 h, l;
#pragma unroll
        for (int j = 0; j < 4; ++j) {
            float x = tile[k4 + j][nr];
            bf16 hv = (bf16)x;
            h[j] = hv;
            l[j] = (bf16)(x - (float)hv);
        }
        *(bf16x4*)(hi + (size_t)(n0 + nr) * CH + k0 + k4) = h;
        *(bf16x4*)(lo + (size_t)(n0 + nr) * CH + k0 + k4) = l;
    }
}

// ---------------------------------------------------------------------------
// bf16-MFMA GEMM, hi/lo split, 64x128 (MxN) tile, BK=32, 256 thr = 4 waves.
// Wave w owns rows [16w,16w+16); acc[8] (32 VGPR). LDS 30 KB -> 4 blocks/CU
// with __launch_bounds__(256,4). R6's proven 2-barrier loop (no dbuf —
// R9 showed occupancy, not pipelining, is what these GEMMs need).
// mode 0: OUT fp32 [b,h,s,d] (+BI, *scale)
// mode 2: OUT fp32 flat [row,512]; BI null -> raw partial (split-K);
//         ML != nullptr fuses the 2-way attn split-softmax merge into loadA.
// mode 3: OBF bf16 [b,h,s, d-swizzled] (K: 16B group g stored at g ^ (s&7))
// mode 4: OBF bf16 [b,h,d, s-chunk-swizzled] (V^T: per 64-k chunk, g ^= d&7)
// ---------------------------------------------------------------------------
__device__ __forceinline__ void gemm_bf16_tile(
    bf16* __restrict__ As_hi, bf16* __restrict__ As_lo,
    bf16* __restrict__ Bs_hi, bf16* __restrict__ Bs_lo,
    const float* __restrict__ IN, const bf16* __restrict__ WThi,
    const bf16* __restrict__ WTlo, const float* __restrict__ BI,
    float* __restrict__ OUT, bf16* __restrict__ OBF,
    const float* __restrict__ ML, float scale, int mode,
    int kbeg, int kiters)
{
    const int t = threadIdx.x;
    const int w = t >> 6;
    const int lane = t & 63;
    const int m16 = lane & 15;
    const int quad = lane >> 4;
    const int m0 = blockIdx.y * 64;
    const int n0 = blockIdx.x * 128;

    const int arow = t >> 2;           // 0..63   (A: 64 rows)
    const int ac8  = (t & 3) << 3;     // 0,8,16,24
    const int brow = t >> 1;           // 0..127  (B: 128 n-rows)
    const int bkc  = (t & 1) << 4;     // 0 or 16

    floatx4 acc[8];
#pragma unroll
    for (int ni = 0; ni < 8; ++ni) {
        acc[ni][0] = 0.f; acc[ni][1] = 0.f;
        acc[ni][2] = 0.f; acc[ni][3] = 0.f;
    }

    float4 af[2];
    bf16x8 pbh[2], pbl[2];

    auto loadA = [&](int k0) {
        if (ML) {
            // fused split-K merge: IN = ctxp [split][b,h,s,d]
            int col = k0 + ac8;                  // multiple of 8
            int hh = col >> 6, dd = col & 63;    // 8 floats stay in one head
            int row = m0 + arow;
            int bb = row >> 11, ss = row & (S_LEN - 1);
            size_t prow = ((size_t)bb * NH + hh) * S_LEN + ss;
            float m0v = ML[prow * 2],                 l0v = ML[prow * 2 + 1];
            float m1v = ML[(ML_STRIDE + prow) * 2],   l1v = ML[(ML_STRIDE + prow) * 2 + 1];
            float mx = fmaxf(m0v, m1v);
            float e0 = __expf(m0v - mx), e1 = __expf(m1v - mx);
            float den = e0 * l0v + e1 * l1v;
            float inv = den > 0.f ? 1.f / den : 0.f;
            float a0 = e0 * inv, a1 = e1 * inv;
            const float* p0 = IN + prow * HD + dd;
            const float* p1 = p0 + CTXP_STRIDE;
#pragma unroll
            for (int j = 0; j < 2; ++j) {
                float4 c0 = ((const float4*)p0)[j];
                float4 c1 = ((const float4*)p1)[j];
                af[j].x = a0 * c0.x + a1 * c1.x;
                af[j].y = a0 * c0.y + a1 * c1.y;
                af[j].z = a0 * c0.z + a1 * c1.z;
                af[j].w = a0 * c0.w + a1 * c1.w;
            }
        } else {
            const float* p = IN + (size_t)(m0 + arow) * CH + k0 + ac8;
            af[0] = ((const float4*)p)[0];
            af[1] = ((const float4*)p)[1];
        }
    };
    auto loadB = [&](int k0) {
        const bf16* ph = WThi + (size_t)(n0 + brow) * CH + k0 + bkc;
        const bf16* pl = WTlo + (size_t)(n0 + brow) * CH + k0 + bkc;
        pbh[0] = ((const bf16x8*)ph)[0]; pbh[1] = ((const bf16x8*)ph)[1];
        pbl[0] = ((const bf16x8*)pl)[0]; pbl[1] = ((const bf16x8*)pl)[1];
    };
    auto stage = [&]() {
        bf16x8 h, l;
#pragma unroll
        for (int j = 0; j < 8; ++j) {
            float x = ((const float*)&af[0])[j];
            bf16 hv = (bf16)x;
            h[j] = hv;
            l[j] = (bf16)(x - (float)hv);
        }
        *(bf16x8*)&As_hi[arow * 40 + ac8] = h;
        *(bf16x8*)&As_lo[arow * 40 + ac8] = l;
        *(bf16x8*)&Bs_hi[brow * 40 + bkc + 0] = pbh[0];
        *(bf16x8*)&Bs_hi[brow * 40 + bkc + 8] = pbh[1];
        *(bf16x8*)&Bs_lo[brow * 40 + bkc + 0] = pbl[0];
        *(bf16x8*)&Bs_lo[brow * 40 + bkc + 8] = pbl[1];
    };

    loadA(kbeg); loadB(kbeg);
    for (int ks = 0; ks < kiters; ++ks) {
        __syncthreads();
        stage();
        __syncthreads();
        if (ks + 1 < kiters) { loadA(kbeg + 32 * (ks + 1)); loadB(kbeg + 32 * (ks + 1)); }

        bf16x8 bh[8], bl[8];
#pragma unroll
        for (int ni = 0; ni < 8; ++ni) {
            bh[ni] = *(const bf16x8*)&Bs_hi[(16 * ni + m16) * 40 + 8 * quad];
            bl[ni] = *(const bf16x8*)&Bs_lo[(16 * ni + m16) * 40 + 8 * quad];
        }
        bf16x8 ah = *(const bf16x8*)&As_hi[(16 * w + m16) * 40 + 8 * quad];
        bf16x8 al = *(const bf16x8*)&As_lo[(16 * w + m16) * 40 + 8 * quad];
#pragma unroll
        for (int ni = 0; ni < 8; ++ni) {
            acc[ni] = __builtin_amdgcn_mfma_f32_16x16x32_bf16(ah, bh[ni], acc[ni], 0, 0, 0);
            acc[ni] = __builtin_amdgcn_mfma_f32_16x16x32_bf16(ah, bl[ni], acc[ni], 0, 0, 0);
            acc[ni] = __builtin_amdgcn_mfma_f32_16x16x32_bf16(al, bh[ni], acc[ni], 0, 0, 0);
        }
    }

#pragma unroll
    for (int r = 0; r < 4; ++r) {
        int row = m0 + 16 * w + 4 * quad + r;
        int bb = row >> 11;
        int ss = row & (S_LEN - 1);
#pragma unroll
        for (int ni = 0; ni < 8; ++ni) {
            int col = n0 + 16 * ni + m16;
            float v = BI ? (acc[ni][r] + BI[col]) * scale
                         : acc[ni][r] * scale;
            if (mode == 0) {
                int hh = col >> 6, dd = col & 63;
                OUT[(((size_t)bb * NH + hh) * S_LEN + ss) * HD + dd] = v;
            } else if (mode == 3) {
                int hh = col >> 6, dd = col & 63;
                OBF[((size_t)(bb * NH + hh) * S_LEN + ss) * HD
                    + (((dd >> 3) ^ (ss & 7)) << 3) + (dd & 7)] = (bf16)v;
            } else if (mode == 4) {
                int hh = col >> 6, dd = col & 63;
                OBF[((size_t)(bb * NH + hh) * HD + dd) * S_LEN
                    + (ss & ~63) + ((((ss >> 3) & 7) ^ (dd & 7)) << 3) + (ss & 7)] = (bf16)v;
            } else {
                OUT[(size_t)row * CH + col] = v;
            }
        }
    }
}

__global__ __launch_bounds__(256, 4) void qkv_gemm_kernel(
    const float* __restrict__ q_in, const float* __restrict__ k_in,
    const float* __restrict__ v_in,
    const bf16* __restrict__ WThi, const bf16* __restrict__ WTlo,
    const float* __restrict__ bq, const float* __restrict__ bk,
    const float* __restrict__ bv,
    float* __restrict__ qp, bf16* __restrict__ kswz, bf16* __restrict__ vswz)
{
    __shared__ __attribute__((aligned(16))) bf16 As_hi[64 * 40];
    __shared__ __attribute__((aligned(16))) bf16 As_lo[64 * 40];
    __shared__ __attribute__((aligned(16))) bf16 Bs_hi[128 * 40];
    __shared__ __attribute__((aligned(16))) bf16 Bs_lo[128 * 40];
    int z = blockIdx.z;
    if (z == 0)
        gemm_bf16_tile(As_hi, As_lo, Bs_hi, Bs_lo, q_in,
                       WThi, WTlo, bq, qp, nullptr, nullptr, 0.125f, 0, 0, 16);
    else if (z == 1)
        gemm_bf16_tile(As_hi, As_lo, Bs_hi, Bs_lo, k_in,
                       WThi + (size_t)CH * CH, WTlo + (size_t)CH * CH, bk,
                       nullptr, kswz, nullptr, 1.0f, 3, 0, 16);
    else
        gemm_bf16_tile(As_hi, As_lo, Bs_hi, Bs_lo, v_in,
                       WThi + (size_t)2 * CH * CH, WTlo + (size_t)2 * CH * CH, bv,
                       nullptr, vswz, nullptr, 1.0f, 4, 0, 16);
}

// out GEMM: split-K x2 into private partials (z = split), fused (m,l) merge.
__global__ __launch_bounds__(256, 4) void out_gemm_kernel(
    const float* __restrict__ ctxp, const float* __restrict__ ml,
    const bf16* __restrict__ WThi, const bf16* __restrict__ WTlo,
    float* __restrict__ outp)
{
    __shared__ __attribute__((aligned(16))) bf16 As_hi[64 * 40];
    __shared__ __attribute__((aligned(16))) bf16 As_lo[64 * 40];
    __shared__ __attribute__((aligned(16))) bf16 Bs_hi[128 * 40];
    __shared__ __attribute__((aligned(16))) bf16 Bs_lo[128 * 40];
    int z = blockIdx.z;
    gemm_bf16_tile(As_hi, As_lo, Bs_hi, Bs_lo, ctxp,
                   WThi + (size_t)3 * CH * CH, WTlo + (size_t)3 * CH * CH,
                   nullptr, outp + (size_t)z * OUTP_STRIDE, nullptr, ml,
                   1.0f, 2, z * 256, 8);
}

// out = partial0 + partial1 + bo
__global__ __launch_bounds__(256) void add_out_kernel(
    const float* __restrict__ outp, const float* __restrict__ bo,
    float* __restrict__ out)
{
    int idx = blockIdx.x * 256 + threadIdx.x;       // one float4
    int col4 = (idx & 127) << 2;
    float4 a = ((const float4*)outp)[idx];
    float4 b = ((const float4*)(outp + OUTP_STRIDE))[idx];
    float4 c = *(const float4*)(bo + col4);
    float4 o;
    o.x = a.x + b.x + c.x;
    o.y = a.y + b.y + c.y;
    o.z = a.z + b.z + c.z;
    o.w = a.w + b.w + c.w;
    ((float4*)out)[idx] = o;
}

// ---------------------------------------------------------------------------
// Flash attention, split-K x2, double-buffered K/V staging (R6, unchanged):
// stage(t+1 -> buf^1) issued BEFORE compute(t); ONE barrier per tile.
// Reuse-aligned XCD swizzle. bias+mask prefetched per-lane in regs.
// ---------------------------------------------------------------------------
__global__ __launch_bounds__(256, 4) void attn_kernel(
    const float* __restrict__ qp, const bf16* __restrict__ kswz,
    const bf16* __restrict__ vswz, const float* __restrict__ bias,
    const void* __restrict__ mask, const int* __restrict__ flagp,
    float* __restrict__ ctxp, float* __restrict__ ml)
{
    __shared__ __attribute__((aligned(16))) bf16 Kt[2][64 * 64];
    __shared__ __attribute__((aligned(16))) bf16 Vt[2][64 * 64];
    __shared__ __attribute__((aligned(16))) bf16 Pbf[64 * 72];

    const int t    = threadIdx.x;
    const int w    = t >> 6;
    const int lane = t & 63;
    const int m16  = lane & 15;
    const int quad = lane >> 4;
    const int mx7  = m16 & 7;

    // physical -> logical block id (bijective: 1024 = 8 XCDs x 128)
    const int p  = blockIdx.x + 32 * (blockIdx.y + 8 * blockIdx.z);
    const int l  = (p & 7) * 128 + (p >> 3);
    const int b  = l & 1;
    const int kz = (l >> 1) & 1;
    const int h  = (l >> 2) & 7;
    const int qi = l >> 5;

    const int q0   = qi * 64;
    const int bh   = b * NH + h;
    const int flag = *flagp;
    const int kbeg = kz * KHALF;

    // Q fragments (prescaled by 1/8 in projection)
    bf16x8 qf[2];
    {
        const float* qrow =
            qp + ((size_t)bh * S_LEN + q0 + 16 * w + m16) * HD + 8 * quad;
#pragma unroll
        for (int c = 0; c < 2; ++c) {
            float4 f0 = *(const float4*)(qrow + 32 * c);
            float4 f1 = *(const float4*)(qrow + 32 * c + 4);
            bf16x8 v;
            v[0] = (bf16)f0.x; v[1] = (bf16)f0.y; v[2] = (bf16)f0.z; v[3] = (bf16)f0.w;
            v[4] = (bf16)f1.x; v[5] = (bf16)f1.y; v[6] = (bf16)f1.z; v[7] = (bf16)f1.w;
            qf[c] = v;
        }
    }

    floatx4 ctxa[4];
    float mrow[4], lrow[4];
#pragma unroll
    for (int tt = 0; tt < 4; ++tt) { ctxa[tt][0]=0.f; ctxa[tt][1]=0.f; ctxa[tt][2]=0.f; ctxa[tt][3]=0.f; }
#pragma unroll
    for (int r = 0; r < 4; ++r) { mrow[r] = NEG_BIG; lrow[r] = 0.f; }

    // per-lane bias/mask prefetch in softmax layout: rows qrow0+r, cols k0+16tt+m16
    const int qrow0 = q0 + 16 * w + 4 * quad;
    const float* bbase = bias + ((size_t)h * S_LEN + qrow0) * S_LEN + m16;
    const unsigned char* mb8  = (const unsigned char*)mask + (size_t)qrow0 * S_LEN + m16;
    const unsigned int*  mb32 = (const unsigned int*)mask  + (size_t)qrow0 * S_LEN + m16;

    float bnext[16]; unsigned mnext[16]; float mb[16];
    auto prefetchBM = [&](int k0) {
        if (flag == 1) {
#pragma unroll
            for (int r = 0; r < 4; ++r)
#pragma unroll
                for (int tt = 0; tt < 4; ++tt)
                    mnext[4 * r + tt] = mb8[(size_t)r * S_LEN + k0 + 16 * tt];
        } else {
#pragma unroll
            for (int r = 0; r < 4; ++r)
#pragma unroll
                for (int tt = 0; tt < 4; ++tt)
                    mnext[4 * r + tt] = mb32[(size_t)r * S_LEN + k0 + 16 * tt];
        }
#pragma unroll
        for (int r = 0; r < 4; ++r)
#pragma unroll
            for (int tt = 0; tt < 4; ++tt)
                bnext[4 * r + tt] = bbase[(size_t)r * S_LEN + k0 + 16 * tt];
    };

    const bf16* kb = kswz + (size_t)bh * S_LEN * HD;
    const bf16* vb = vswz + (size_t)bh * HD * S_LEN;
    const int lrow8 = lane >> 3;         // row within 8-row chunk
    const int lcol8 = (lane & 7) * 8;    // bf16 offset of 16B group

    // wave w stages chunks {2w, 2w+1} (8 rows x 128B each) of K and V
    auto stageKV = [&](int k0, int buf) {
#pragma unroll
        for (int i = 0; i < 2; ++i) {
            int c = 2 * w + i;
            int row = 8 * c + lrow8;
            gll16(kb + (size_t)(k0 + row) * HD + lcol8, &Kt[buf][c * 512]);
            gll16(vb + (size_t)row * S_LEN + k0 + lcol8, &Vt[buf][c * 512]);
        }
    };

    prefetchBM(kbeg);
    stageKV(kbeg, 0);
    __syncthreads();           // drains the prologue stage (vmcnt(0) implicit)
    int cur = 0;

    for (int k0 = kbeg; k0 < kbeg + KHALF; k0 += 64) {
        const bool more = (k0 + 64 < kbeg + KHALF);
        if (more) stageKV(k0 + 64, cur ^ 1);   // issue next tile into other buf

        // select masked bias for this tile, then prefetch next (overlaps compute)
#pragma unroll
        for (int j = 0; j < 16; ++j) mb[j] = mnext[j] ? bnext[j] : NEG_BIG;
        if (more) prefetchBM(k0 + 64);

        // QK^T  (Kt read with XOR(g, row&7) de-swizzle)
        const bf16* Kc = Kt[cur];
        const bf16* Vc = Vt[cur];
        floatx4 sc[4];
#pragma unroll
        for (int tt = 0; tt < 4; ++tt) { sc[tt][0]=0.f; sc[tt][1]=0.f; sc[tt][2]=0.f; sc[tt][3]=0.f; }
#pragma unroll
        for (int st = 0; st < 2; ++st)
#pragma unroll
            for (int tt = 0; tt < 4; ++tt) {
                bf16x8 kf = *(const bf16x8*)&Kc[(16 * tt + m16) * 64
                                                + (((quad + 4 * st) ^ mx7) << 3)];
                sc[tt] = __builtin_amdgcn_mfma_f32_16x16x32_bf16(qf[st], kf, sc[tt], 0, 0, 0);
            }

        // online softmax (bias/mask already in regs)
        float alpha[4];
#pragma unroll
        for (int r = 0; r < 4; ++r) {
            int lrowq = 16 * w + 4 * quad + r;
            float s[4];
#pragma unroll
            for (int tt = 0; tt < 4; ++tt)
                s[tt] = sc[tt][r] + mb[4 * r + tt];
            float mx = fmaxf(fmaxf(s[0], s[1]), fmaxf(s[2], s[3]));
            mx = fmaxf(mx, __shfl_xor(mx, 1));
            mx = fmaxf(mx, __shfl_xor(mx, 2));
            mx = fmaxf(mx, __shfl_xor(mx, 4));
            mx = fmaxf(mx, __shfl_xor(mx, 8));
            float mnew = fmaxf(mrow[r], mx);
            float al = __expf(mrow[r] - mnew);
            float ls = 0.f;
#pragma unroll
            for (int tt = 0; tt < 4; ++tt) {
                float px = (s[tt] <= -1e37f) ? 0.f : __expf(s[tt] - mnew);
                ls += px;
                Pbf[lrowq * 72 + 16 * tt + m16] = (bf16)px;
            }
            ls += __shfl_xor(ls, 1);
            ls += __shfl_xor(ls, 2);
            ls += __shfl_xor(ls, 4);
            ls += __shfl_xor(ls, 8);
            lrow[r] = lrow[r] * al + ls;
            mrow[r] = mnew;
            alpha[r] = al;
        }
#pragma unroll
        for (int tt = 0; tt < 4; ++tt)
#pragma unroll
            for (int r = 0; r < 4; ++r) ctxa[tt][r] *= alpha[r];

        // PV (Pbf rows 16w..16w+15 wave-private -> no barrier vs softmax)
#pragma unroll
        for (int st = 0; st < 2; ++st) {
            bf16x8 pf = *(const bf16x8*)&Pbf[(16 * w + m16) * 72 + 8 * quad + 32 * st];
#pragma unroll
            for (int tt = 0; tt < 4; ++tt) {
                bf16x8 vf = *(const bf16x8*)&Vc[(16 * tt + m16) * 64
                                                + (((quad + 4 * st) ^ mx7) << 3)];
                ctxa[tt] = __builtin_amdgcn_mfma_f32_16x16x32_bf16(pf, vf, ctxa[tt], 0, 0, 0);
            }
        }

        __syncthreads();
        cur ^= 1;
    }

    // epilogue: unnormalized partial ctx + (m,l) for this split
    float* cp = ctxp + (size_t)kz * CTXP_STRIDE;
#pragma unroll
    for (int r = 0; r < 4; ++r) {
        int grow = q0 + 16 * w + 4 * quad + r;
        size_t prow = (size_t)bh * S_LEN + grow;
#pragma unroll
        for (int tt = 0; tt < 4; ++tt)
            cp[prow * HD + 16 * tt + m16] = ctxa[tt][r];
        if (m16 == 0) {
            ml[((size_t)kz * ML_STRIDE + prow) * 2 + 0] = mrow[r];
            ml[((size_t)kz * ML_STRIDE + prow) * 2 + 1] = lrow[r];
        }
    }
}

extern "C" void kernel_launch(void* const* d_in, const int* in_sizes, int n_in,
                              void* d_out, int out_size, void* d_ws, size_t ws_size,
                              hipStream_t stream) {
    const float* k_in = (const float*)d_in[0];
    const float* v_in = (const float*)d_in[1];
    const float* q_in = (const float*)d_in[2];
    const void*  mask = d_in[3];
    const float* bias = (const float*)d_in[4];
    const float* Wq = (const float*)d_in[5];
    const float* bq = (const float*)d_in[6];
    const float* Wk = (const float*)d_in[7];
    const float* bk = (const float*)d_in[8];
    const float* Wv = (const float*)d_in[9];
    const float* bv = (const float*)d_in[10];
    const float* Wo = (const float*)d_in[11];
    const float* bo = (const float*)d_in[12];
    float* out = (float*)d_out;

    // Workspace 53 MB (+4 B). ws_size >= 54 MB proven in round 5.
    char* base = (char*)d_ws;
    float* qp   = (float*)(base);                    // 8 MB [B,H,S,D] fp32
    float* ctxp = (float*)(base + (8u  << 20));      // 16 MB attn partials
    float* mlb  = (float*)(base + (24u << 20));      // 0.5 MB (m,l) x 2 splits
    bf16*  kswz = (bf16*) (base + (25u << 20));      // 4 MB K bf16 swizzled
    bf16*  vswz = (bf16*) (base + (29u << 20));      // 4 MB V^T bf16 swizzled
    bf16*  WThi = (bf16*) (base + (33u << 20));      // 2 MB
    bf16*  WTlo = (bf16*) (base + (35u << 20));      // 2 MB
    float* outp = (float*)(base + (37u << 20));      // 16 MB out partials (2x8)
    int*   flag = (int*)  (base + (53u << 20));

    detect_mask_kernel<<<1, 256, 0, stream>>>((const unsigned char*)mask, flag);
    prep_weights_kernel<<<dim3(8, 8, 4), 256, 0, stream>>>(
        Wq, Wk, Wv, Wo, WThi, WTlo);
    qkv_gemm_kernel<<<dim3(4, 64, 3), 256, 0, stream>>>(
        q_in, k_in, v_in, WThi, WTlo, bq, bk, bv, qp, kswz, vswz);
    attn_kernel<<<dim3(32, 8, 4), 256, 0, stream>>>(
        qp, kswz, vswz, bias, mask, flag, ctxp, mlb);
    out_gemm_kernel<<<dim3(4, 64, 2), 256, 0, stream>>>(
        ctxp, mlb, WThi, WTlo, outp);
    add_out_kernel<<<2048, 256, 0, stream>>>(outp, bo, out);
}